// Round 4
// baseline (273.559 us; speedup 1.0000x reference)
//
#include <hip/hip_runtime.h>
#include <stdint.h>

// MultiHeadAttention: B=2, S=2048, HIDDEN=1024, NH=16, HD=64, causal.
// R4: attention load-balance + VALU diet.
//  - qt remap: block i<256 -> qt=i&15 (bh 0..15); i>=256 -> qt=15-(i&15)
//    (bh 16..31). Under round-robin dispatch blocks i,i+256 share a CU ->
//    every CU gets qt + (15-qt) = uniform 17 block-steps (was 2..32).
//  - Q pre-scaled by log2e/8 in gemm_qkv epilogue -> p = exp2(s), single
//    v_exp_f32 (was mul + exp-lowering mul + exp).
//  - P stored to LDS with truncating f2bf (1 op); l is MFMA-ones on the SAME
//    truncated P, so normalization exactly cancels truncation bias.
// MFMA 16x16x32 bf16 layouts (HW-verified):
//   A/B frag: lane holds row[m=lane&15][k=(lane>>4)*8 + j]
//   C/D:      row=(lane>>4)*4+reg, col=lane&15

#define HIDDEN 1024
#define NH 16
#define HD 64
#define BATCH 2
#define SEQ 2048

typedef unsigned short u16;
typedef unsigned int u32;
typedef __attribute__((ext_vector_type(8))) short short8;   // 8 bf16
typedef __attribute__((ext_vector_type(4))) float f32x4;

__device__ __forceinline__ u16 f2bf(float f) {
    u32 u = __float_as_uint(f);
    return (u16)((u + 0x7FFFu + ((u >> 16) & 1u)) >> 16);   // RNE
}

// ---------------- fused fp32 -> bf16 conversion (x + 4 weights) -----------
__global__ void cvt_all(const float* __restrict__ x, const float* __restrict__ Wq,
                        const float* __restrict__ Wk, const float* __restrict__ Wv,
                        const float* __restrict__ Wo, u16* __restrict__ xb,
                        u16* __restrict__ wqb, u16* __restrict__ wkb,
                        u16* __restrict__ wvb, u16* __restrict__ wob) {
    const int blk = blockIdx.x;
    const float* src; u16* dst; int base;
    if (blk < 2048)      { src = x;  dst = xb;  base = blk; }
    else if (blk < 2560) { src = Wq; dst = wqb; base = blk - 2048; }
    else if (blk < 3072) { src = Wk; dst = wkb; base = blk - 2560; }
    else if (blk < 3584) { src = Wv; dst = wvb; base = blk - 3072; }
    else                 { src = Wo; dst = wob; base = blk - 3584; }
    const int i = base * 256 + threadIdx.x;
    float4 a = ((const float4*)src)[2 * i];
    float4 b = ((const float4*)src)[2 * i + 1];
    union { u16 h[8]; uint4 v; } o;
    o.h[0] = f2bf(a.x); o.h[1] = f2bf(a.y); o.h[2] = f2bf(a.z); o.h[3] = f2bf(a.w);
    o.h[4] = f2bf(b.x); o.h[5] = f2bf(b.y); o.h[6] = f2bf(b.z); o.h[7] = f2bf(b.w);
    ((uint4*)dst)[i] = o.v;
}

// ---------------- shared GEMM K-loop (128x128 tile, BK=32) ----------------
#define GEMM_LDA 40
__device__ __forceinline__ void gemm_kloop(const u16* __restrict__ A,
                                           const u16* __restrict__ Wt,
                                           u16* As, u16* Bs, f32x4 (*acc)[4],
                                           int m0, int n0, int t) {
    const int lane = t & 63;
    const int w = t >> 6;
    const int quad = lane >> 4;
    const int lm = lane & 15;
    const int wm = (w & 1) * 64;
    const int wn = (w >> 1) * 64;
    const int srow = t >> 2;
    const int schunk = (t & 3) * 8;
    for (int k0 = 0; k0 < 1024; k0 += 32) {
        uint4 a0 = *(const uint4*)(A + (size_t)(m0 + srow) * 1024 + k0 + schunk);
        uint4 a1 = *(const uint4*)(A + (size_t)(m0 + srow + 64) * 1024 + k0 + schunk);
        uint4 b0 = *(const uint4*)(Wt + (size_t)(n0 + srow) * 1024 + k0 + schunk);
        uint4 b1 = *(const uint4*)(Wt + (size_t)(n0 + srow + 64) * 1024 + k0 + schunk);
        __syncthreads();
        *(uint4*)(As + srow * GEMM_LDA + schunk) = a0;
        *(uint4*)(As + (srow + 64) * GEMM_LDA + schunk) = a1;
        *(uint4*)(Bs + srow * GEMM_LDA + schunk) = b0;
        *(uint4*)(Bs + (srow + 64) * GEMM_LDA + schunk) = b1;
        __syncthreads();
        short8 af[4], bf[4];
#pragma unroll
        for (int mi = 0; mi < 4; mi++)
            af[mi] = *(const short8*)(As + (wm + mi * 16 + lm) * GEMM_LDA + quad * 8);
#pragma unroll
        for (int ni = 0; ni < 4; ni++)
            bf[ni] = *(const short8*)(Bs + (wn + ni * 16 + lm) * GEMM_LDA + quad * 8);
#pragma unroll
        for (int mi = 0; mi < 4; mi++)
#pragma unroll
            for (int ni = 0; ni < 4; ni++)
                acc[mi][ni] = __builtin_amdgcn_mfma_f32_16x16x32_bf16(
                    af[mi], bf[ni], acc[mi][ni], 0, 0, 0);
    }
}

// ---------------- fused QKV projection ------------------------------------
// grid (24, 32): blockIdx.x>>3 selects {Q,K,V}; Q/K -> [B,H,S,D], V -> [B,H,D,S].
// Q is additionally scaled by log2e/8 (folds softmax scale + exp2 base).
__launch_bounds__(256, 2)
__global__ void gemm_qkv(const u16* __restrict__ A, const u16* __restrict__ Wqb,
                         const u16* __restrict__ Wkb, const u16* __restrict__ Wvb,
                         const float* __restrict__ bq, const float* __restrict__ bk,
                         const float* __restrict__ bv, u16* __restrict__ Qo,
                         u16* __restrict__ Ko, u16* __restrict__ Vo) {
    __shared__ u16 As[128 * GEMM_LDA];
    __shared__ u16 Bs[128 * GEMM_LDA];
    const int which = blockIdx.x >> 3;
    const int n0 = (blockIdx.x & 7) * 128;
    const int m0 = blockIdx.y * 128;
    const u16* Wt = (which == 0) ? Wqb : (which == 1) ? Wkb : Wvb;
    const float* bias = (which == 0) ? bq : (which == 1) ? bk : bv;
    u16* out = (which == 0) ? Qo : (which == 1) ? Ko : Vo;
    const float oscale = (which == 0) ? 0.18033688011112042f : 1.0f;  // log2e/8
    const int t = threadIdx.x;
    const int lane = t & 63, w = t >> 6, quad = lane >> 4, lm = lane & 15;
    const int wm = (w & 1) * 64, wn = (w >> 1) * 64;

    f32x4 acc[4][4] = {};
    gemm_kloop(A, Wt, As, Bs, acc, m0, n0, t);

#pragma unroll
    for (int ni = 0; ni < 4; ni++) {
        const int n = n0 + wn + ni * 16 + lm;
        const float bv_ = bias[n];
        const int h = n >> 6, d = n & 63;
#pragma unroll
        for (int mi = 0; mi < 4; mi++)
#pragma unroll
            for (int r = 0; r < 4; r++) {
                const int m = m0 + wm + mi * 16 + quad * 4 + r;
                const int b = m >> 11, s = m & 2047;
                const u16 hv = f2bf((acc[mi][ni][r] + bv_) * oscale);
                if (which == 2)
                    out[(((size_t)(b * NH + h) * HD + d) * SEQ) + s] = hv;
                else
                    out[(((size_t)(b * NH + h) * SEQ + s) * HD) + d] = hv;
            }
    }
}

// ---------------- output projection (fp32 out + bias) ---------------------
__launch_bounds__(256, 2)
__global__ void gemm_out(const u16* __restrict__ A, const u16* __restrict__ Wt,
                         const float* __restrict__ bias, float* __restrict__ out) {
    __shared__ u16 As[128 * GEMM_LDA];
    __shared__ u16 Bs[128 * GEMM_LDA];
    const int n0 = blockIdx.x * 128;
    const int m0 = blockIdx.y * 128;
    const int t = threadIdx.x;
    const int lane = t & 63, w = t >> 6, quad = lane >> 4, lm = lane & 15;
    const int wm = (w & 1) * 64, wn = (w >> 1) * 64;

    f32x4 acc[4][4] = {};
    gemm_kloop(A, Wt, As, Bs, acc, m0, n0, t);

#pragma unroll
    for (int ni = 0; ni < 4; ni++) {
        const int n = n0 + wn + ni * 16 + lm;
        const float bv_ = bias[n];
#pragma unroll
        for (int mi = 0; mi < 4; mi++)
#pragma unroll
            for (int r = 0; r < 4; r++) {
                const int m = m0 + wm + mi * 16 + quad * 4 + r;
                out[(size_t)m * 1024 + n] = acc[mi][ni][r] + bv_;
            }
    }
}

// ---------------- flash attention, causal, no-max softmax -----------------
// Grid 512 blocks, 256 thr = 4 waves; wave owns 32 q-rows; K-tile 128.
// qt remapped so co-scheduled blocks have complementary work (uniform CUs).
// Q comes pre-scaled by log2e/8 => p = exp2(s) directly.
__launch_bounds__(256, 2)
__global__ void attn_kernel(const u16* __restrict__ Q, const u16* __restrict__ K,
                            const u16* __restrict__ Vt, u16* __restrict__ Out) {
    constexpr int LDK = 72;    // 64 + 8
    constexpr int LDV = 136;   // 128 + 8
    constexpr int LDP = 132;   // 128 + 4
    __shared__ u16 Ks[128 * LDK];
    __shared__ u16 Vs[64 * LDV];
    __shared__ u16 Ps[4 * 32 * LDP];
    const int t = threadIdx.x;
    const int lane = t & 63, w = t >> 6, quad = lane >> 4, lm = lane & 15;
    // complementary-qt remap
    const int pair = blockIdx.x & 255;
    const int half = blockIdx.x >> 8;
    const int qt = half ? (15 - (pair & 15)) : (pair & 15);
    const int bh = (pair >> 4) | (half << 4);   // 0..31
    const int b = bh >> 4, h = bh & 15;
    const size_t base = (size_t)(b * NH + h) * SEQ * HD;
    const u16* Qg = Q + base;
    const u16* Kg = K + base;
    const u16* Vg = Vt + base;
    const int q0 = qt * 128 + w * 32;

    short8 qf[2][2];
#pragma unroll
    for (int m = 0; m < 2; m++)
#pragma unroll
        for (int kk = 0; kk < 2; kk++)
            qf[m][kk] = *(const short8*)(Qg + (size_t)(q0 + m * 16 + lm) * HD + kk * 32 + quad * 8);

    f32x4 oacc[2][4] = {};
    f32x4 lacc[2] = {};
    short8 ones;
#pragma unroll
    for (int j = 0; j < 8; j++) ones[j] = (short)0x3F80;   // bf16 1.0

    u16* Pw = Ps + w * 32 * LDP;

    for (int kt = 0; kt <= qt; kt++) {
        // stage K (128x64) and V^T (64x128) via registers
        uint4 kv[4], vv[4];
#pragma unroll
        for (int j = 0; j < 4; j++) {
            const int idx = j * 256 + t;
            kv[j] = *(const uint4*)(Kg + (size_t)(kt * 128 + (idx >> 3)) * HD + (idx & 7) * 8);
            vv[j] = *(const uint4*)(Vg + (size_t)(idx >> 4) * SEQ + kt * 128 + (idx & 15) * 8);
        }
        __syncthreads();   // prior iter's LDS reads done
#pragma unroll
        for (int j = 0; j < 4; j++) {
            const int idx = j * 256 + t;
            *(uint4*)(Ks + (idx >> 3) * LDK + (idx & 7) * 8) = kv[j];
            *(uint4*)(Vs + (idx >> 4) * LDV + (idx & 15) * 8) = vv[j];
        }
        __syncthreads();

        // S = Q K^T : 32 q-rows x 128 keys per wave (S already in log2 units)
        f32x4 sacc[2][8];
#pragma unroll
        for (int n = 0; n < 8; n++) {
            short8 kf0 = *(const short8*)(Ks + (n * 16 + lm) * LDK + quad * 8);
            short8 kf1 = *(const short8*)(Ks + (n * 16 + lm) * LDK + 32 + quad * 8);
#pragma unroll
            for (int m = 0; m < 2; m++) {
                f32x4 a = {};
                a = __builtin_amdgcn_mfma_f32_16x16x32_bf16(qf[m][0], kf0, a, 0, 0, 0);
                a = __builtin_amdgcn_mfma_f32_16x16x32_bf16(qf[m][1], kf1, a, 0, 0, 0);
                sacc[m][n] = a;
            }
        }
        // p = exp2(s); causal mask on diagonal tile (p=0).
        const bool diag = (kt == qt);
#pragma unroll
        for (int m = 0; m < 2; m++)
#pragma unroll
            for (int n = 0; n < 8; n++)
#pragma unroll
                for (int r = 0; r < 4; r++) {
                    float s = sacc[m][n][r];
                    if (diag && (n * 16 + lm > w * 32 + m * 16 + quad * 4 + r))
                        s = -__builtin_inff();
                    sacc[m][n][r] = exp2f(s);
                }
        // P: C-layout regs -> per-wave LDS (truncating bf16; l renormalizes)
#pragma unroll
        for (int m = 0; m < 2; m++)
#pragma unroll
            for (int n = 0; n < 8; n++)
#pragma unroll
                for (int r = 0; r < 4; r++)
                    Pw[(m * 16 + quad * 4 + r) * LDP + n * 16 + lm] =
                        (u16)(__float_as_uint(sacc[m][n][r]) >> 16);
        short8 pf[2][4];
#pragma unroll
        for (int m = 0; m < 2; m++)
#pragma unroll
            for (int k4 = 0; k4 < 4; k4++)
                pf[m][k4] = *(const short8*)(Pw + (m * 16 + lm) * LDP + k4 * 32 + quad * 8);
        // O += P V ; l += P 1
#pragma unroll
        for (int n = 0; n < 4; n++)
#pragma unroll
            for (int k4 = 0; k4 < 4; k4++) {
                short8 vf = *(const short8*)(Vs + (n * 16 + lm) * LDV + k4 * 32 + quad * 8);
#pragma unroll
                for (int m = 0; m < 2; m++)
                    oacc[m][n] = __builtin_amdgcn_mfma_f32_16x16x32_bf16(pf[m][k4], vf, oacc[m][n], 0, 0, 0);
            }
#pragma unroll
        for (int m = 0; m < 2; m++)
#pragma unroll
            for (int k4 = 0; k4 < 4; k4++)
                lacc[m] = __builtin_amdgcn_mfma_f32_16x16x32_bf16(pf[m][k4], ones, lacc[m], 0, 0, 0);
    }

    // epilogue: every lane holds its rows' l in lacc[m][r]
#pragma unroll
    for (int m = 0; m < 2; m++) {
        float inv[4];
#pragma unroll
        for (int r = 0; r < 4; r++) inv[r] = 1.0f / lacc[m][r];
#pragma unroll
        for (int n = 0; n < 4; n++)
#pragma unroll
            for (int r = 0; r < 4; r++) {
                const int qq = q0 + m * 16 + quad * 4 + r;
                Out[(size_t)(b * SEQ + qq) * HIDDEN + h * HD + n * 16 + lm] =
                    f2bf(oacc[m][n][r] * inv[r]);
            }
    }
}

// ---------------- launcher ------------------------------------------------
extern "C" void kernel_launch(void* const* d_in, const int* in_sizes, int n_in,
                              void* d_out, int out_size, void* d_ws, size_t ws_size,
                              hipStream_t stream) {
    const float* x  = (const float*)d_in[0];
    const float* Wq = (const float*)d_in[1];
    const float* bq = (const float*)d_in[2];
    const float* Wk = (const float*)d_in[3];
    const float* bk = (const float*)d_in[4];
    const float* Wv = (const float*)d_in[5];
    const float* bv = (const float*)d_in[6];
    const float* Wo = (const float*)d_in[7];
    const float* bo = (const float*)d_in[8];
    float* out = (float*)d_out;

    char* ws = (char*)d_ws;
    const size_t SZ_X = (size_t)4096 * 1024 * 2;   // 8 MB bf16
    const size_t SZ_W = (size_t)1024 * 1024 * 2;   // 2 MB bf16
    u16* xb    = (u16*)(ws);
    u16* wqb   = (u16*)(ws + SZ_X);
    u16* wkb   = (u16*)(ws + SZ_X + SZ_W);
    u16* wvb   = (u16*)(ws + SZ_X + 2 * SZ_W);
    u16* wob   = (u16*)(ws + SZ_X + 3 * SZ_W);
    u16* Qb    = (u16*)(ws + SZ_X + 4 * SZ_W);
    u16* Kb    = (u16*)(ws + 2 * SZ_X + 4 * SZ_W);
    u16* Vtb   = (u16*)(ws + 3 * SZ_X + 4 * SZ_W);
    u16* attnb = (u16*)(ws + 4 * SZ_X + 4 * SZ_W);

    cvt_all<<<4096, 256, 0, stream>>>(x, Wq, Wk, Wv, Wo, xb, wqb, wkb, wvb, wob);
    gemm_qkv<<<dim3(24, 32), 256, 0, stream>>>(xb, wqb, wkb, wvb, bq, bk, bv, Qb, Kb, Vtb);
    attn_kernel<<<BATCH * NH * (SEQ / 128), 256, 0, stream>>>(Qb, Kb, Vtb, attnb);
    gemm_out<<<dim3(8, 32), 256, 0, stream>>>(attnb, wob, bo, out);
}

// Round 5
// 245.928 us; speedup vs baseline: 1.1124x; 1.1124x over previous
//
#include <hip/hip_runtime.h>
#include <stdint.h>

// MultiHeadAttention: B=2, S=2048, HIDDEN=1024, NH=16, HD=64, causal.
// R5: attention pipelining. K-tile 64 with double-buffered LDS (one barrier
//     per step; staging overlaps compute), depth-2 register prefetch of K/V
//     (global latency hidden across 2 barriers), causal mask only on last 2
//     steps. Keeps R4 math: Q pre-scaled log2e/8 -> exp2, truncating P store,
//     l via MFMA-ones (renormalizes P truncation exactly), complementary-qt
//     remap. LDS 54.3 KB -> 2 blocks/CU.
// MFMA 16x16x32 bf16 layouts (HW-verified):
//   A/B frag: lane holds row[m=lane&15][k=(lane>>4)*8 + j]
//   C/D:      row=(lane>>4)*4+reg, col=lane&15

#define HIDDEN 1024
#define NH 16
#define HD 64
#define BATCH 2
#define SEQ 2048

typedef unsigned short u16;
typedef unsigned int u32;
typedef __attribute__((ext_vector_type(8))) short short8;   // 8 bf16
typedef __attribute__((ext_vector_type(4))) float f32x4;

__device__ __forceinline__ u16 f2bf(float f) {
    u32 u = __float_as_uint(f);
    return (u16)((u + 0x7FFFu + ((u >> 16) & 1u)) >> 16);   // RNE
}

// ---------------- fused fp32 -> bf16 conversion (x + 4 weights) -----------
__global__ void cvt_all(const float* __restrict__ x, const float* __restrict__ Wq,
                        const float* __restrict__ Wk, const float* __restrict__ Wv,
                        const float* __restrict__ Wo, u16* __restrict__ xb,
                        u16* __restrict__ wqb, u16* __restrict__ wkb,
                        u16* __restrict__ wvb, u16* __restrict__ wob) {
    const int blk = blockIdx.x;
    const float* src; u16* dst; int base;
    if (blk < 2048)      { src = x;  dst = xb;  base = blk; }
    else if (blk < 2560) { src = Wq; dst = wqb; base = blk - 2048; }
    else if (blk < 3072) { src = Wk; dst = wkb; base = blk - 2560; }
    else if (blk < 3584) { src = Wv; dst = wvb; base = blk - 3072; }
    else                 { src = Wo; dst = wob; base = blk - 3584; }
    const int i = base * 256 + threadIdx.x;
    float4 a = ((const float4*)src)[2 * i];
    float4 b = ((const float4*)src)[2 * i + 1];
    union { u16 h[8]; uint4 v; } o;
    o.h[0] = f2bf(a.x); o.h[1] = f2bf(a.y); o.h[2] = f2bf(a.z); o.h[3] = f2bf(a.w);
    o.h[4] = f2bf(b.x); o.h[5] = f2bf(b.y); o.h[6] = f2bf(b.z); o.h[7] = f2bf(b.w);
    ((uint4*)dst)[i] = o.v;
}

// ---------------- shared GEMM K-loop (128x128 tile, BK=32) ----------------
#define GEMM_LDA 40
__device__ __forceinline__ void gemm_kloop(const u16* __restrict__ A,
                                           const u16* __restrict__ Wt,
                                           u16* As, u16* Bs, f32x4 (*acc)[4],
                                           int m0, int n0, int t) {
    const int lane = t & 63;
    const int w = t >> 6;
    const int quad = lane >> 4;
    const int lm = lane & 15;
    const int wm = (w & 1) * 64;
    const int wn = (w >> 1) * 64;
    const int srow = t >> 2;
    const int schunk = (t & 3) * 8;
    for (int k0 = 0; k0 < 1024; k0 += 32) {
        uint4 a0 = *(const uint4*)(A + (size_t)(m0 + srow) * 1024 + k0 + schunk);
        uint4 a1 = *(const uint4*)(A + (size_t)(m0 + srow + 64) * 1024 + k0 + schunk);
        uint4 b0 = *(const uint4*)(Wt + (size_t)(n0 + srow) * 1024 + k0 + schunk);
        uint4 b1 = *(const uint4*)(Wt + (size_t)(n0 + srow + 64) * 1024 + k0 + schunk);
        __syncthreads();
        *(uint4*)(As + srow * GEMM_LDA + schunk) = a0;
        *(uint4*)(As + (srow + 64) * GEMM_LDA + schunk) = a1;
        *(uint4*)(Bs + srow * GEMM_LDA + schunk) = b0;
        *(uint4*)(Bs + (srow + 64) * GEMM_LDA + schunk) = b1;
        __syncthreads();
        short8 af[4], bf[4];
#pragma unroll
        for (int mi = 0; mi < 4; mi++)
            af[mi] = *(const short8*)(As + (wm + mi * 16 + lm) * GEMM_LDA + quad * 8);
#pragma unroll
        for (int ni = 0; ni < 4; ni++)
            bf[ni] = *(const short8*)(Bs + (wn + ni * 16 + lm) * GEMM_LDA + quad * 8);
#pragma unroll
        for (int mi = 0; mi < 4; mi++)
#pragma unroll
            for (int ni = 0; ni < 4; ni++)
                acc[mi][ni] = __builtin_amdgcn_mfma_f32_16x16x32_bf16(
                    af[mi], bf[ni], acc[mi][ni], 0, 0, 0);
    }
}

// ---------------- fused QKV projection ------------------------------------
// grid (24, 32): blockIdx.x>>3 selects {Q,K,V}; Q/K -> [B,H,S,D], V -> [B,H,D,S].
// Q additionally scaled by log2e/8 (folds softmax scale + exp2 base).
__launch_bounds__(256, 2)
__global__ void gemm_qkv(const u16* __restrict__ A, const u16* __restrict__ Wqb,
                         const u16* __restrict__ Wkb, const u16* __restrict__ Wvb,
                         const float* __restrict__ bq, const float* __restrict__ bk,
                         const float* __restrict__ bv, u16* __restrict__ Qo,
                         u16* __restrict__ Ko, u16* __restrict__ Vo) {
    __shared__ u16 As[128 * GEMM_LDA];
    __shared__ u16 Bs[128 * GEMM_LDA];
    const int which = blockIdx.x >> 3;
    const int n0 = (blockIdx.x & 7) * 128;
    const int m0 = blockIdx.y * 128;
    const u16* Wt = (which == 0) ? Wqb : (which == 1) ? Wkb : Wvb;
    const float* bias = (which == 0) ? bq : (which == 1) ? bk : bv;
    u16* out = (which == 0) ? Qo : (which == 1) ? Ko : Vo;
    const float oscale = (which == 0) ? 0.18033688011112042f : 1.0f;  // log2e/8
    const int t = threadIdx.x;
    const int lane = t & 63, w = t >> 6, quad = lane >> 4, lm = lane & 15;
    const int wm = (w & 1) * 64, wn = (w >> 1) * 64;

    f32x4 acc[4][4] = {};
    gemm_kloop(A, Wt, As, Bs, acc, m0, n0, t);

#pragma unroll
    for (int ni = 0; ni < 4; ni++) {
        const int n = n0 + wn + ni * 16 + lm;
        const float bv_ = bias[n];
        const int h = n >> 6, d = n & 63;
#pragma unroll
        for (int mi = 0; mi < 4; mi++)
#pragma unroll
            for (int r = 0; r < 4; r++) {
                const int m = m0 + wm + mi * 16 + quad * 4 + r;
                const int b = m >> 11, s = m & 2047;
                const u16 hv = f2bf((acc[mi][ni][r] + bv_) * oscale);
                if (which == 2)
                    out[(((size_t)(b * NH + h) * HD + d) * SEQ) + s] = hv;
                else
                    out[(((size_t)(b * NH + h) * SEQ + s) * HD) + d] = hv;
            }
    }
}

// ---------------- output projection (fp32 out + bias) ---------------------
__launch_bounds__(256, 2)
__global__ void gemm_out(const u16* __restrict__ A, const u16* __restrict__ Wt,
                         const float* __restrict__ bias, float* __restrict__ out) {
    __shared__ u16 As[128 * GEMM_LDA];
    __shared__ u16 Bs[128 * GEMM_LDA];
    const int n0 = blockIdx.x * 128;
    const int m0 = blockIdx.y * 128;
    const int t = threadIdx.x;
    const int lane = t & 63, w = t >> 6, quad = lane >> 4, lm = lane & 15;
    const int wm = (w & 1) * 64, wn = (w >> 1) * 64;

    f32x4 acc[4][4] = {};
    gemm_kloop(A, Wt, As, Bs, acc, m0, n0, t);

#pragma unroll
    for (int ni = 0; ni < 4; ni++) {
        const int n = n0 + wn + ni * 16 + lm;
        const float bv_ = bias[n];
#pragma unroll
        for (int mi = 0; mi < 4; mi++)
#pragma unroll
            for (int r = 0; r < 4; r++) {
                const int m = m0 + wm + mi * 16 + quad * 4 + r;
                out[(size_t)m * 1024 + n] = acc[mi][ni][r] + bv_;
            }
    }
}

// ---------------- flash attention, causal, pipelined ----------------------
// Grid 512 blocks, 256 thr = 4 waves; wave owns 32 q-rows; Q-tile 128,
// K-tile 64, double-buffered LDS (1 barrier/step), depth-2 reg prefetch.
__launch_bounds__(256, 2)
__global__ void attn_kernel(const u16* __restrict__ Q, const u16* __restrict__ K,
                            const u16* __restrict__ Vt, u16* __restrict__ Out) {
    constexpr int LDK = 72;   // 64 + 8
    constexpr int LDV = 72;   // 64 + 8
    constexpr int LDP = 68;   // 64 + 4
    __shared__ u16 Ks[2][64 * LDK];   // 18432 B
    __shared__ u16 Vs[2][64 * LDV];   // 18432 B
    __shared__ u16 Ps[4 * 32 * LDP];  // 17408 B  -> total 54272 B
    const int t = threadIdx.x;
    const int lane = t & 63, w = t >> 6, quad = lane >> 4, lm = lane & 15;
    // complementary-qt remap (kept from R4; harmless under any dispatch)
    const int pair = blockIdx.x & 255;
    const int half = blockIdx.x >> 8;
    const int qt = half ? (15 - (pair & 15)) : (pair & 15);
    const int bh = (pair >> 4) | (half << 4);
    const int b = bh >> 4, h = bh & 15;
    const size_t base = (size_t)(b * NH + h) * SEQ * HD;
    const u16* Qg = Q + base;
    const u16* Kg = K + base;
    const u16* Vg = Vt + base;
    const int q0 = qt * 128 + w * 32;
    const int nk = 2 * qt + 2;   // number of 64-key steps

    short8 qf[2][2];
#pragma unroll
    for (int m = 0; m < 2; m++)
#pragma unroll
        for (int kk = 0; kk < 2; kk++)
            qf[m][kk] = *(const short8*)(Qg + (size_t)(q0 + m * 16 + lm) * HD + kk * 32 + quad * 8);

    f32x4 oacc[2][4] = {};
    f32x4 lacc[2] = {};
    short8 ones;
#pragma unroll
    for (int j = 0; j < 8; j++) ones[j] = (short)0x3F80;   // bf16 1.0

    u16* Pw = Ps + w * 32 * LDP;
    // per-thread staging coords: i = j*256+t, row = i>>3 (0..63), chunk=(i&7)*8
    const int srow0 = t >> 3, schunk = (t & 7) * 8;   // j=0 row; j=1 row = srow0+32

    // ---- depth-2 register prefetch pipeline ----
    uint4 kva[2][2], vva[2][2];
#pragma unroll
    for (int p = 0; p < 2; p++) {
        const int kt = (p < nk) ? p : (nk - 1);
#pragma unroll
        for (int j = 0; j < 2; j++) {
            const int row = srow0 + j * 32;
            kva[p][j] = *(const uint4*)(Kg + (size_t)(kt * 64 + row) * HD + schunk);
            vva[p][j] = *(const uint4*)(Vg + (size_t)row * SEQ + kt * 64 + schunk);
        }
    }
    // store tile 0 -> buf 0
#pragma unroll
    for (int j = 0; j < 2; j++) {
        const int row = srow0 + j * 32;
        *(uint4*)(&Ks[0][row * LDK + schunk]) = kva[0][j];
        *(uint4*)(&Vs[0][row * LDV + schunk]) = vva[0][j];
    }

    for (int kt = 0; kt < nk; kt++) {
        const int cur = kt & 1;
        const int nxt = cur ^ 1;
        __syncthreads();   // buf[cur] (stored last iter / preamble) now visible

        // issue global loads for tile kt+2 into slot cur (its tile was stored)
        if (kt + 2 < nk) {
#pragma unroll
            for (int j = 0; j < 2; j++) {
                const int row = srow0 + j * 32;
                kva[cur][j] = *(const uint4*)(Kg + (size_t)((kt + 2) * 64 + row) * HD + schunk);
                vva[cur][j] = *(const uint4*)(Vg + (size_t)row * SEQ + (kt + 2) * 64 + schunk);
            }
        }
        // store tile kt+1 (slot nxt) -> buf[nxt]; overlaps compute below
        if (kt + 1 < nk) {
#pragma unroll
            for (int j = 0; j < 2; j++) {
                const int row = srow0 + j * 32;
                *(uint4*)(&Ks[nxt][row * LDK + schunk]) = kva[nxt][j];
                *(uint4*)(&Vs[nxt][row * LDV + schunk]) = vva[nxt][j];
            }
        }

        const u16* Kc = Ks[cur];
        const u16* Vc = Vs[cur];

        // S = Q K^T : 32 q-rows x 64 keys per wave (log2-units)
        f32x4 sacc[2][4];
#pragma unroll
        for (int n = 0; n < 4; n++) {
            short8 kf0 = *(const short8*)(Kc + (n * 16 + lm) * LDK + quad * 8);
            short8 kf1 = *(const short8*)(Kc + (n * 16 + lm) * LDK + 32 + quad * 8);
#pragma unroll
            for (int m = 0; m < 2; m++) {
                f32x4 a = {};
                a = __builtin_amdgcn_mfma_f32_16x16x32_bf16(qf[m][0], kf0, a, 0, 0, 0);
                a = __builtin_amdgcn_mfma_f32_16x16x32_bf16(qf[m][1], kf1, a, 0, 0, 0);
                sacc[m][n] = a;
            }
        }
        // p = exp2(s); causal mask only in the last two steps
        if (kt >= 2 * qt) {
            const int kbase = kt * 64 - qt * 128 - w * 32;  // key - qrow offset
#pragma unroll
            for (int m = 0; m < 2; m++)
#pragma unroll
                for (int n = 0; n < 4; n++)
#pragma unroll
                    for (int r = 0; r < 4; r++)
                        if (kbase + n * 16 + lm > m * 16 + quad * 4 + r)
                            sacc[m][n][r] = -__builtin_inff();
        }
#pragma unroll
        for (int m = 0; m < 2; m++)
#pragma unroll
            for (int n = 0; n < 4; n++)
#pragma unroll
                for (int r = 0; r < 4; r++)
                    Pw[(m * 16 + quad * 4 + r) * LDP + n * 16 + lm] =
                        (u16)(__float_as_uint(exp2f(sacc[m][n][r])) >> 16);
        short8 pf[2][2];
#pragma unroll
        for (int m = 0; m < 2; m++)
#pragma unroll
            for (int k4 = 0; k4 < 2; k4++)
                pf[m][k4] = *(const short8*)(Pw + (m * 16 + lm) * LDP + k4 * 32 + quad * 8);
        // O += P V ; l += P 1
#pragma unroll
        for (int n = 0; n < 4; n++)
#pragma unroll
            for (int k4 = 0; k4 < 2; k4++) {
                short8 vf = *(const short8*)(Vc + (n * 16 + lm) * LDV + k4 * 32 + quad * 8);
#pragma unroll
                for (int m = 0; m < 2; m++)
                    oacc[m][n] = __builtin_amdgcn_mfma_f32_16x16x32_bf16(pf[m][k4], vf, oacc[m][n], 0, 0, 0);
            }
#pragma unroll
        for (int m = 0; m < 2; m++)
#pragma unroll
            for (int k4 = 0; k4 < 2; k4++)
                lacc[m] = __builtin_amdgcn_mfma_f32_16x16x32_bf16(pf[m][k4], ones, lacc[m], 0, 0, 0);
    }

    // epilogue
#pragma unroll
    for (int m = 0; m < 2; m++) {
        float inv[4];
#pragma unroll
        for (int r = 0; r < 4; r++) inv[r] = 1.0f / lacc[m][r];
#pragma unroll
        for (int n = 0; n < 4; n++)
#pragma unroll
            for (int r = 0; r < 4; r++) {
                const int qq = q0 + m * 16 + quad * 4 + r;
                Out[(size_t)(b * SEQ + qq) * HIDDEN + h * HD + n * 16 + lm] =
                    f2bf(oacc[m][n][r] * inv[r]);
            }
    }
}

// ---------------- launcher ------------------------------------------------
extern "C" void kernel_launch(void* const* d_in, const int* in_sizes, int n_in,
                              void* d_out, int out_size, void* d_ws, size_t ws_size,
                              hipStream_t stream) {
    const float* x  = (const float*)d_in[0];
    const float* Wq = (const float*)d_in[1];
    const float* bq = (const float*)d_in[2];
    const float* Wk = (const float*)d_in[3];
    const float* bk = (const float*)d_in[4];
    const float* Wv = (const float*)d_in[5];
    const float* bv = (const float*)d_in[6];
    const float* Wo = (const float*)d_in[7];
    const float* bo = (const float*)d_in[8];
    float* out = (float*)d_out;

    char* ws = (char*)d_ws;
    const size_t SZ_X = (size_t)4096 * 1024 * 2;   // 8 MB bf16
    const size_t SZ_W = (size_t)1024 * 1024 * 2;   // 2 MB bf16
    u16* xb    = (u16*)(ws);
    u16* wqb   = (u16*)(ws + SZ_X);
    u16* wkb   = (u16*)(ws + SZ_X + SZ_W);
    u16* wvb   = (u16*)(ws + SZ_X + 2 * SZ_W);
    u16* wob   = (u16*)(ws + SZ_X + 3 * SZ_W);
    u16* Qb    = (u16*)(ws + SZ_X + 4 * SZ_W);
    u16* Kb    = (u16*)(ws + 2 * SZ_X + 4 * SZ_W);
    u16* Vtb   = (u16*)(ws + 3 * SZ_X + 4 * SZ_W);
    u16* attnb = (u16*)(ws + 4 * SZ_X + 4 * SZ_W);

    cvt_all<<<4096, 256, 0, stream>>>(x, Wq, Wk, Wv, Wo, xb, wqb, wkb, wvb, wob);
    gemm_qkv<<<dim3(24, 32), 256, 0, stream>>>(xb, wqb, wkb, wvb, bq, bk, bv, Qb, Kb, Vtb);
    attn_kernel<<<BATCH * NH * (SEQ / 128), 256, 0, stream>>>(Qb, Kb, Vtb, attnb);
    gemm_out<<<dim3(8, 32), 256, 0, stream>>>(attnb, wob, bo, out);
}

// Round 6
// 244.803 us; speedup vs baseline: 1.1175x; 1.0046x over previous
//
#include <hip/hip_runtime.h>
#include <stdint.h>

// MultiHeadAttention: B=2, S=2048, HIDDEN=1024, NH=16, HD=64, causal.
// R6: attention TLP/balance. Q-tile 64 (wave=16 q-rows), grid 1024 blocks
//     dispatched longest-first (qt = 31 - idx>>5) so short blocks backfill;
//     LDS 44.5 KB -> 3 blocks/CU (12 waves). Keeps R5 pipeline: K-tile 64,
//     double-buffered LDS (1 barrier/step), depth-2 register prefetch, exp2
//     math (Q pre-scaled log2e/8), truncating P store, l via MFMA-ones.
// MFMA 16x16x32 bf16 layouts (HW-verified):
//   A/B frag: lane holds row[m=lane&15][k=(lane>>4)*8 + j]
//   C/D:      row=(lane>>4)*4+reg, col=lane&15

#define HIDDEN 1024
#define NH 16
#define HD 64
#define BATCH 2
#define SEQ 2048

typedef unsigned short u16;
typedef unsigned int u32;
typedef __attribute__((ext_vector_type(8))) short short8;   // 8 bf16
typedef __attribute__((ext_vector_type(4))) float f32x4;

__device__ __forceinline__ u16 f2bf(float f) {
    u32 u = __float_as_uint(f);
    return (u16)((u + 0x7FFFu + ((u >> 16) & 1u)) >> 16);   // RNE
}

// ---------------- fused fp32 -> bf16 conversion (x + 4 weights) -----------
__global__ void cvt_all(const float* __restrict__ x, const float* __restrict__ Wq,
                        const float* __restrict__ Wk, const float* __restrict__ Wv,
                        const float* __restrict__ Wo, u16* __restrict__ xb,
                        u16* __restrict__ wqb, u16* __restrict__ wkb,
                        u16* __restrict__ wvb, u16* __restrict__ wob) {
    const int blk = blockIdx.x;
    const float* src; u16* dst; int base;
    if (blk < 2048)      { src = x;  dst = xb;  base = blk; }
    else if (blk < 2560) { src = Wq; dst = wqb; base = blk - 2048; }
    else if (blk < 3072) { src = Wk; dst = wkb; base = blk - 2560; }
    else if (blk < 3584) { src = Wv; dst = wvb; base = blk - 3072; }
    else                 { src = Wo; dst = wob; base = blk - 3584; }
    const int i = base * 256 + threadIdx.x;
    float4 a = ((const float4*)src)[2 * i];
    float4 b = ((const float4*)src)[2 * i + 1];
    union { u16 h[8]; uint4 v; } o;
    o.h[0] = f2bf(a.x); o.h[1] = f2bf(a.y); o.h[2] = f2bf(a.z); o.h[3] = f2bf(a.w);
    o.h[4] = f2bf(b.x); o.h[5] = f2bf(b.y); o.h[6] = f2bf(b.z); o.h[7] = f2bf(b.w);
    ((uint4*)dst)[i] = o.v;
}

// ---------------- shared GEMM K-loop (128x128 tile, BK=32) ----------------
#define GEMM_LDA 40
__device__ __forceinline__ void gemm_kloop(const u16* __restrict__ A,
                                           const u16* __restrict__ Wt,
                                           u16* As, u16* Bs, f32x4 (*acc)[4],
                                           int m0, int n0, int t) {
    const int lane = t & 63;
    const int w = t >> 6;
    const int quad = lane >> 4;
    const int lm = lane & 15;
    const int wm = (w & 1) * 64;
    const int wn = (w >> 1) * 64;
    const int srow = t >> 2;
    const int schunk = (t & 3) * 8;
    for (int k0 = 0; k0 < 1024; k0 += 32) {
        uint4 a0 = *(const uint4*)(A + (size_t)(m0 + srow) * 1024 + k0 + schunk);
        uint4 a1 = *(const uint4*)(A + (size_t)(m0 + srow + 64) * 1024 + k0 + schunk);
        uint4 b0 = *(const uint4*)(Wt + (size_t)(n0 + srow) * 1024 + k0 + schunk);
        uint4 b1 = *(const uint4*)(Wt + (size_t)(n0 + srow + 64) * 1024 + k0 + schunk);
        __syncthreads();
        *(uint4*)(As + srow * GEMM_LDA + schunk) = a0;
        *(uint4*)(As + (srow + 64) * GEMM_LDA + schunk) = a1;
        *(uint4*)(Bs + srow * GEMM_LDA + schunk) = b0;
        *(uint4*)(Bs + (srow + 64) * GEMM_LDA + schunk) = b1;
        __syncthreads();
        short8 af[4], bf[4];
#pragma unroll
        for (int mi = 0; mi < 4; mi++)
            af[mi] = *(const short8*)(As + (wm + mi * 16 + lm) * GEMM_LDA + quad * 8);
#pragma unroll
        for (int ni = 0; ni < 4; ni++)
            bf[ni] = *(const short8*)(Bs + (wn + ni * 16 + lm) * GEMM_LDA + quad * 8);
#pragma unroll
        for (int mi = 0; mi < 4; mi++)
#pragma unroll
            for (int ni = 0; ni < 4; ni++)
                acc[mi][ni] = __builtin_amdgcn_mfma_f32_16x16x32_bf16(
                    af[mi], bf[ni], acc[mi][ni], 0, 0, 0);
    }
}

// ---------------- fused QKV projection ------------------------------------
// grid (24, 32): blockIdx.x>>3 selects {Q,K,V}; Q/K -> [B,H,S,D], V -> [B,H,D,S].
// Q additionally scaled by log2e/8 (folds softmax scale + exp2 base).
__launch_bounds__(256, 2)
__global__ void gemm_qkv(const u16* __restrict__ A, const u16* __restrict__ Wqb,
                         const u16* __restrict__ Wkb, const u16* __restrict__ Wvb,
                         const float* __restrict__ bq, const float* __restrict__ bk,
                         const float* __restrict__ bv, u16* __restrict__ Qo,
                         u16* __restrict__ Ko, u16* __restrict__ Vo) {
    __shared__ u16 As[128 * GEMM_LDA];
    __shared__ u16 Bs[128 * GEMM_LDA];
    const int which = blockIdx.x >> 3;
    const int n0 = (blockIdx.x & 7) * 128;
    const int m0 = blockIdx.y * 128;
    const u16* Wt = (which == 0) ? Wqb : (which == 1) ? Wkb : Wvb;
    const float* bias = (which == 0) ? bq : (which == 1) ? bk : bv;
    u16* out = (which == 0) ? Qo : (which == 1) ? Ko : Vo;
    const float oscale = (which == 0) ? 0.18033688011112042f : 1.0f;  // log2e/8
    const int t = threadIdx.x;
    const int lane = t & 63, w = t >> 6, quad = lane >> 4, lm = lane & 15;
    const int wm = (w & 1) * 64, wn = (w >> 1) * 64;

    f32x4 acc[4][4] = {};
    gemm_kloop(A, Wt, As, Bs, acc, m0, n0, t);

#pragma unroll
    for (int ni = 0; ni < 4; ni++) {
        const int n = n0 + wn + ni * 16 + lm;
        const float bv_ = bias[n];
        const int h = n >> 6, d = n & 63;
#pragma unroll
        for (int mi = 0; mi < 4; mi++)
#pragma unroll
            for (int r = 0; r < 4; r++) {
                const int m = m0 + wm + mi * 16 + quad * 4 + r;
                const int b = m >> 11, s = m & 2047;
                const u16 hv = f2bf((acc[mi][ni][r] + bv_) * oscale);
                if (which == 2)
                    out[(((size_t)(b * NH + h) * HD + d) * SEQ) + s] = hv;
                else
                    out[(((size_t)(b * NH + h) * SEQ + s) * HD) + d] = hv;
            }
    }
}

// ---------------- output projection (fp32 out + bias) ---------------------
__launch_bounds__(256, 2)
__global__ void gemm_out(const u16* __restrict__ A, const u16* __restrict__ Wt,
                         const float* __restrict__ bias, float* __restrict__ out) {
    __shared__ u16 As[128 * GEMM_LDA];
    __shared__ u16 Bs[128 * GEMM_LDA];
    const int n0 = blockIdx.x * 128;
    const int m0 = blockIdx.y * 128;
    const int t = threadIdx.x;
    const int lane = t & 63, w = t >> 6, quad = lane >> 4, lm = lane & 15;
    const int wm = (w & 1) * 64, wn = (w >> 1) * 64;

    f32x4 acc[4][4] = {};
    gemm_kloop(A, Wt, As, Bs, acc, m0, n0, t);

#pragma unroll
    for (int ni = 0; ni < 4; ni++) {
        const int n = n0 + wn + ni * 16 + lm;
        const float bv_ = bias[n];
#pragma unroll
        for (int mi = 0; mi < 4; mi++)
#pragma unroll
            for (int r = 0; r < 4; r++) {
                const int m = m0 + wm + mi * 16 + quad * 4 + r;
                out[(size_t)m * 1024 + n] = acc[mi][ni][r] + bv_;
            }
    }
}

// ---------------- flash attention, causal, pipelined ----------------------
// Grid 1024 blocks (longest-first), 256 thr = 4 waves; wave owns 16 q-rows;
// Q-tile 64, K-tile 64, double-buffered LDS, depth-2 reg prefetch.
// LDS 44.5 KB -> 3 blocks/CU.
__launch_bounds__(256, 3)
__global__ void attn_kernel(const u16* __restrict__ Q, const u16* __restrict__ K,
                            const u16* __restrict__ Vt, u16* __restrict__ Out) {
    constexpr int LDK = 72;   // 64 + 8
    constexpr int LDV = 72;   // 64 + 8
    constexpr int LDP = 68;   // 64 + 4
    __shared__ u16 Ks[2][64 * LDK];   // 18432 B
    __shared__ u16 Vs[2][64 * LDV];   // 18432 B
    __shared__ u16 Ps[4 * 16 * LDP];  //  8704 B  -> total 45568 B
    const int t = threadIdx.x;
    const int lane = t & 63, w = t >> 6, quad = lane >> 4, lm = lane & 15;
    // longest-first: early blocks get the largest qt
    const int qt = 31 - (blockIdx.x >> 5);   // 0..31
    const int bh = blockIdx.x & 31;
    const int b = bh >> 4, h = bh & 15;
    const size_t base = (size_t)(b * NH + h) * SEQ * HD;
    const u16* Qg = Q + base;
    const u16* Kg = K + base;
    const u16* Vg = Vt + base;
    const int q0 = qt * 64 + w * 16;
    const int nk = qt + 1;   // number of 64-key steps

    short8 qf[2];
#pragma unroll
    for (int kk = 0; kk < 2; kk++)
        qf[kk] = *(const short8*)(Qg + (size_t)(q0 + lm) * HD + kk * 32 + quad * 8);

    f32x4 oacc[4] = {};
    f32x4 lacc = {};
    short8 ones;
#pragma unroll
    for (int j = 0; j < 8; j++) ones[j] = (short)0x3F80;   // bf16 1.0

    u16* Pw = Ps + w * 16 * LDP;
    const int srow0 = t >> 3, schunk = (t & 7) * 8;   // rows srow0, srow0+32

    // ---- depth-2 register prefetch pipeline ----
    uint4 kva[2][2], vva[2][2];
#pragma unroll
    for (int p = 0; p < 2; p++) {
        const int kt = (p < nk) ? p : (nk - 1);
#pragma unroll
        for (int j = 0; j < 2; j++) {
            const int row = srow0 + j * 32;
            kva[p][j] = *(const uint4*)(Kg + (size_t)(kt * 64 + row) * HD + schunk);
            vva[p][j] = *(const uint4*)(Vg + (size_t)row * SEQ + kt * 64 + schunk);
        }
    }
#pragma unroll
    for (int j = 0; j < 2; j++) {
        const int row = srow0 + j * 32;
        *(uint4*)(&Ks[0][row * LDK + schunk]) = kva[0][j];
        *(uint4*)(&Vs[0][row * LDV + schunk]) = vva[0][j];
    }

    for (int kt = 0; kt < nk; kt++) {
        const int cur = kt & 1;
        const int nxt = cur ^ 1;
        __syncthreads();   // buf[cur] (stored last iter / preamble) now visible

        // issue global loads for tile kt+2 into slot cur
        if (kt + 2 < nk) {
#pragma unroll
            for (int j = 0; j < 2; j++) {
                const int row = srow0 + j * 32;
                kva[cur][j] = *(const uint4*)(Kg + (size_t)((kt + 2) * 64 + row) * HD + schunk);
                vva[cur][j] = *(const uint4*)(Vg + (size_t)row * SEQ + (kt + 2) * 64 + schunk);
            }
        }
        // store tile kt+1 -> buf[nxt]; overlaps compute below
        if (kt + 1 < nk) {
#pragma unroll
            for (int j = 0; j < 2; j++) {
                const int row = srow0 + j * 32;
                *(uint4*)(&Ks[nxt][row * LDK + schunk]) = kva[nxt][j];
                *(uint4*)(&Vs[nxt][row * LDV + schunk]) = vva[nxt][j];
            }
        }

        const u16* Kc = Ks[cur];
        const u16* Vc = Vs[cur];

        // S = Q K^T : 16 q-rows x 64 keys per wave (log2-units)
        f32x4 sacc[4];
#pragma unroll
        for (int n = 0; n < 4; n++) {
            short8 kf0 = *(const short8*)(Kc + (n * 16 + lm) * LDK + quad * 8);
            short8 kf1 = *(const short8*)(Kc + (n * 16 + lm) * LDK + 32 + quad * 8);
            f32x4 a = {};
            a = __builtin_amdgcn_mfma_f32_16x16x32_bf16(qf[0], kf0, a, 0, 0, 0);
            a = __builtin_amdgcn_mfma_f32_16x16x32_bf16(qf[1], kf1, a, 0, 0, 0);
            sacc[n] = a;
        }
        // causal mask only on the diagonal tile
        if (kt == qt) {
            const int qrow = w * 16 + quad * 4;   // + r
#pragma unroll
            for (int n = 0; n < 4; n++)
#pragma unroll
                for (int r = 0; r < 4; r++)
                    if (n * 16 + lm > qrow + r - (w * 16))  // key > qrow within tile
                        ;  // placeholder (real mask below)
            // NOTE: keys within tile are n*16+lm (0..63); q within tile is
            // w*16+quad*4+r (0..63). Mask keys > q.
#pragma unroll
            for (int n = 0; n < 4; n++)
#pragma unroll
                for (int r = 0; r < 4; r++)
                    if (n * 16 + lm > w * 16 + quad * 4 + r)
                        sacc[n][r] = -__builtin_inff();
        }
        // p = exp2(s) -> truncating bf16 -> per-wave LDS (l renormalizes)
#pragma unroll
        for (int n = 0; n < 4; n++)
#pragma unroll
            for (int r = 0; r < 4; r++)
                Pw[(quad * 4 + r) * LDP + n * 16 + lm] =
                    (u16)(__float_as_uint(exp2f(sacc[n][r])) >> 16);
        short8 pf[2];
#pragma unroll
        for (int k4 = 0; k4 < 2; k4++)
            pf[k4] = *(const short8*)(Pw + lm * LDP + k4 * 32 + quad * 8);
        // O += P V ; l += P 1
#pragma unroll
        for (int n = 0; n < 4; n++)
#pragma unroll
            for (int k4 = 0; k4 < 2; k4++) {
                short8 vf = *(const short8*)(Vc + (n * 16 + lm) * LDV + k4 * 32 + quad * 8);
                oacc[n] = __builtin_amdgcn_mfma_f32_16x16x32_bf16(pf[k4], vf, oacc[n], 0, 0, 0);
            }
#pragma unroll
        for (int k4 = 0; k4 < 2; k4++)
            lacc = __builtin_amdgcn_mfma_f32_16x16x32_bf16(pf[k4], ones, lacc, 0, 0, 0);
    }

    // epilogue
    float inv[4];
#pragma unroll
    for (int r = 0; r < 4; r++) inv[r] = 1.0f / lacc[r];
#pragma unroll
    for (int n = 0; n < 4; n++)
#pragma unroll
        for (int r = 0; r < 4; r++) {
            const int qq = q0 + quad * 4 + r;
            Out[(size_t)(b * SEQ + qq) * HIDDEN + h * HD + n * 16 + lm] =
                f2bf(oacc[n][r] * inv[r]);
        }
}

// ---------------- launcher ------------------------------------------------
extern "C" void kernel_launch(void* const* d_in, const int* in_sizes, int n_in,
                              void* d_out, int out_size, void* d_ws, size_t ws_size,
                              hipStream_t stream) {
    const float* x  = (const float*)d_in[0];
    const float* Wq = (const float*)d_in[1];
    const float* bq = (const float*)d_in[2];
    const float* Wk = (const float*)d_in[3];
    const float* bk = (const float*)d_in[4];
    const float* Wv = (const float*)d_in[5];
    const float* bv = (const float*)d_in[6];
    const float* Wo = (const float*)d_in[7];
    const float* bo = (const float*)d_in[8];
    float* out = (float*)d_out;

    char* ws = (char*)d_ws;
    const size_t SZ_X = (size_t)4096 * 1024 * 2;   // 8 MB bf16
    const size_t SZ_W = (size_t)1024 * 1024 * 2;   // 2 MB bf16
    u16* xb    = (u16*)(ws);
    u16* wqb   = (u16*)(ws + SZ_X);
    u16* wkb   = (u16*)(ws + SZ_X + SZ_W);
    u16* wvb   = (u16*)(ws + SZ_X + 2 * SZ_W);
    u16* wob   = (u16*)(ws + SZ_X + 3 * SZ_W);
    u16* Qb    = (u16*)(ws + SZ_X + 4 * SZ_W);
    u16* Kb    = (u16*)(ws + 2 * SZ_X + 4 * SZ_W);
    u16* Vtb   = (u16*)(ws + 3 * SZ_X + 4 * SZ_W);
    u16* attnb = (u16*)(ws + 4 * SZ_X + 4 * SZ_W);

    cvt_all<<<4096, 256, 0, stream>>>(x, Wq, Wk, Wv, Wo, xb, wqb, wkb, wvb, wob);
    gemm_qkv<<<dim3(24, 32), 256, 0, stream>>>(xb, wqb, wkb, wvb, bq, bk, bv, Qb, Kb, Vtb);
    attn_kernel<<<BATCH * NH * (SEQ / 64), 256, 0, stream>>>(Qb, Kb, Vtb, attnb);
    gemm_out<<<dim3(8, 32), 256, 0, stream>>>(attnb, wob, bo, out);
}